// Round 4
// baseline (98.371 us; speedup 1.0000x reference)
//
#include <hip/hip_runtime.h>

// GAT layer, B=8, N=1024, INP=7, hidden=64, D=32, H=4.
// Algebra: softmax_j(s_i + s_j + ba) == softmax_j(s_j) (shift-invariance), so
// attention weights and G[b,h,:] = sum_j p[j,h] fx[j,:] are i-independent;
// every output row of batch b equals (concat_h G[b,h,:]/Z[b,h]) @ Ws + bs.
//
// R4: single fused kernel. Phase A: block-cooperative LDS-tiled MLP (R3 k1,
// which fixed R1/R2's scratch-spill: VGPR=72 < ~140 live) producing per-block
// G/Z partials. Grid-wide spin barrier (256 blocks co-resident by
// construction: ~53 KB LDS -> 3 blocks/CU capacity >= grid). Phase B: reduce
// partials, normalize, project through Ws, broadcast-write a 32-row slice.
// Counter zeroed by a 4-byte hipMemsetAsync node (ws is poisoned 0xAA).

#define BB 8
#define NN 1024
#define TR 32            // rows per block (phase A)
#define NB 256           // blocks; 32 per batch

__global__ __launch_bounds__(256) void gat_fused(
    const float* __restrict__ x,
    const float* __restrict__ W1, const float* __restrict__ b1,
    const float* __restrict__ W2, const float* __restrict__ b2,
    const float* __restrict__ W3, const float* __restrict__ b3,
    const float* __restrict__ Wa,
    const float* __restrict__ Ws, const float* __restrict__ bs,
    float* __restrict__ Gp, float* __restrict__ Zp,
    unsigned int* __restrict__ ctr,
    float* __restrict__ out)
{
    const int t   = threadIdx.x;
    const int blk = blockIdx.x;

    __shared__ float W1s[7 * 64];     // [k][o]
    __shared__ float W2s[64 * 64];    // [k][o]
    __shared__ float W3s[64 * 32];    // [k][o]
    __shared__ float Was[32 * 4];     // Wa rows 32..63: [k][h]
    __shared__ float b1s[64], b2s[64], b3s[32];
    __shared__ float xs[TR * 8];      // [r][k], stride 8
    __shared__ float h1s[TR * 68];    // stride 68 (pad 4, keeps 16B align)
    __shared__ float h2s[TR * 68];
    __shared__ float fxs[TR * 36];    // stride 36
    __shared__ float es[TR * 4];      // e[r][h]
    // phase B
    __shared__ float Gsh[128];
    __shared__ float Gc[128];
    __shared__ float zsh[4];
    __shared__ float red[8 * 32];
    __shared__ float orow[32];

    // =============================== Phase A ===============================
    // ---- stage weights + x tile ----
    {
        const float4* s2 = (const float4*)W2;
        float4* d2 = (float4*)W2s;
        d2[t] = s2[t]; d2[t + 256] = s2[t + 256];
        d2[t + 512] = s2[t + 512]; d2[t + 768] = s2[t + 768];
        const float4* s3 = (const float4*)W3;
        float4* d3 = (float4*)W3s;
        d3[t] = s3[t]; d3[t + 256] = s3[t + 256];
        if (t < 112) ((float4*)W1s)[t] = ((const float4*)W1)[t];
        if (t < 32)  ((float4*)Was)[t] = ((const float4*)Wa)[32 + t]; // rows 32..63
        if (t < 16)  ((float4*)b1s)[t] = ((const float4*)b1)[t];
        if (t >= 16 && t < 32) ((float4*)b2s)[t - 16] = ((const float4*)b2)[t - 16];
        if (t >= 32 && t < 40) ((float4*)b3s)[t - 32] = ((const float4*)b3)[t - 32];
        if (t < TR * 7) xs[(t / 7) * 8 + (t % 7)] = x[blk * (TR * 7) + t];
    }
    __syncthreads();

    // ---- layer 1: [7]->[64], lrelu. 1 row x 8 cols per thread ----
    {
        const int r  = t >> 3;
        const int o0 = (t & 7) * 8;
        float acc[8];
#pragma unroll
        for (int j = 0; j < 8; ++j) acc[j] = b1s[o0 + j];
#pragma unroll
        for (int k = 0; k < 7; ++k) {
            const float xv = xs[r * 8 + k];
#pragma unroll
            for (int j = 0; j < 8; ++j)
                acc[j] = fmaf(xv, W1s[k * 64 + o0 + j], acc[j]);
        }
#pragma unroll
        for (int j = 0; j < 8; ++j)
            h1s[r * 68 + o0 + j] = fmaxf(acc[j], 0.2f * acc[j]);
    }
    __syncthreads();

    // ---- layer 2: [64]->[64], lrelu. 2 rows x 4 cols per thread ----
    {
        const int o0 = (t & 15) * 4;
        const int r0 = (t >> 4) * 2;
        float a0[4], a1[4];
#pragma unroll
        for (int j = 0; j < 4; ++j) { a0[j] = b2s[o0 + j]; a1[j] = b2s[o0 + j]; }
#pragma unroll
        for (int k4 = 0; k4 < 64; k4 += 4) {
            const float4 hA = *(const float4*)&h1s[r0 * 68 + k4];
            const float4 hB = *(const float4*)&h1s[(r0 + 1) * 68 + k4];
            const float ha[4] = {hA.x, hA.y, hA.z, hA.w};
            const float hb[4] = {hB.x, hB.y, hB.z, hB.w};
#pragma unroll
            for (int kk = 0; kk < 4; ++kk) {
                const float4 w = *(const float4*)&W2s[(k4 + kk) * 64 + o0];
                a0[0] = fmaf(ha[kk], w.x, a0[0]); a0[1] = fmaf(ha[kk], w.y, a0[1]);
                a0[2] = fmaf(ha[kk], w.z, a0[2]); a0[3] = fmaf(ha[kk], w.w, a0[3]);
                a1[0] = fmaf(hb[kk], w.x, a1[0]); a1[1] = fmaf(hb[kk], w.y, a1[1]);
                a1[2] = fmaf(hb[kk], w.z, a1[2]); a1[3] = fmaf(hb[kk], w.w, a1[3]);
            }
        }
        *(float4*)&h2s[r0 * 68 + o0] = make_float4(
            fmaxf(a0[0], 0.2f * a0[0]), fmaxf(a0[1], 0.2f * a0[1]),
            fmaxf(a0[2], 0.2f * a0[2]), fmaxf(a0[3], 0.2f * a0[3]));
        *(float4*)&h2s[(r0 + 1) * 68 + o0] = make_float4(
            fmaxf(a1[0], 0.2f * a1[0]), fmaxf(a1[1], 0.2f * a1[1]),
            fmaxf(a1[2], 0.2f * a1[2]), fmaxf(a1[3], 0.2f * a1[3]));
    }
    __syncthreads();

    // ---- layer 3: [64]->[32]. 1 row x 4 cols per thread ----
    {
        const int r  = t >> 3;
        const int o0 = (t & 7) * 4;
        float acc[4];
#pragma unroll
        for (int j = 0; j < 4; ++j) acc[j] = b3s[o0 + j];
#pragma unroll
        for (int k4 = 0; k4 < 64; k4 += 4) {
            const float4 hv = *(const float4*)&h2s[r * 68 + k4];
            const float hh[4] = {hv.x, hv.y, hv.z, hv.w};
#pragma unroll
            for (int kk = 0; kk < 4; ++kk) {
                const float4 w = *(const float4*)&W3s[(k4 + kk) * 32 + o0];
                acc[0] = fmaf(hh[kk], w.x, acc[0]); acc[1] = fmaf(hh[kk], w.y, acc[1]);
                acc[2] = fmaf(hh[kk], w.z, acc[2]); acc[3] = fmaf(hh[kk], w.w, acc[3]);
            }
        }
        *(float4*)&fxs[r * 36 + o0] = make_float4(acc[0], acc[1], acc[2], acc[3]);
    }
    __syncthreads();

    // ---- e[r][h] = exp(fx[r,:] . Wa2[:,h])  (no max-sub: s_j is O(1)) ----
    if (t < TR * 4) {
        const int r = t >> 2, h = t & 3;
        float s = 0.f;
#pragma unroll 8
        for (int k = 0; k < 32; ++k) s = fmaf(fxs[r * 36 + k], Was[k * 4 + h], s);
        es[r * 4 + h] = __expf(s);
    }
    __syncthreads();

    // ---- block partials: G[h][d] (128 threads), Z[h] (4 threads) ----
    if (t < 128) {
        const int h = t >> 5, d = t & 31;
        float g = 0.f;
#pragma unroll 8
        for (int r = 0; r < TR; ++r) g = fmaf(es[r * 4 + h], fxs[r * 36 + d], g);
        Gp[blk * 128 + t] = g;
    } else if (t < 132) {
        const int h = t - 128;
        float z = 0.f;
#pragma unroll 8
        for (int r = 0; r < TR; ++r) z += es[r * 4 + h];
        Zp[blk * 4 + h] = z;
    }

    // ========================= grid-wide barrier ==========================
    __syncthreads();
    if (t == 0) {
        __threadfence();  // release our Gp/Zp partials (agent scope)
        __hip_atomic_fetch_add(ctr, 1u, __ATOMIC_ACQ_REL,
                               __HIP_MEMORY_SCOPE_AGENT);
        while (__hip_atomic_load(ctr, __ATOMIC_RELAXED,
                                 __HIP_MEMORY_SCOPE_AGENT) < NB) { }
        __threadfence();  // acquire everyone's partials
    }
    __syncthreads();

    // =============================== Phase B ===============================
    const int b     = blk >> 5;       // 32 blocks per batch
    const int slice = blk & 31;       // each writes 32 rows

    if (t < 128) {
        const float* gp = Gp + (size_t)(b * 32) * 128 + t;
        float g = 0.f;
#pragma unroll 8
        for (int i = 0; i < 32; ++i) g += gp[i * 128];
        Gsh[t] = g;
    } else if (t < 132) {
        const int h = t - 128;
        float z = 0.f;
#pragma unroll 8
        for (int i = 0; i < 32; ++i) z += Zp[(b * 32 + i) * 4 + h];
        zsh[h] = z;
    }
    __syncthreads();
    if (t < 128) Gc[t] = Gsh[t] / zsh[t >> 5];
    __syncthreads();

    // orow[o] = bs[o] + sum_k Gc[k] * Ws[k*32+o]; k split over 8 groups
    {
        const int o = t & 31, p = t >> 5;
        float a = (p == 0) ? bs[o] : 0.f;
#pragma unroll
        for (int kk = 0; kk < 16; ++kk) {
            const int k = p * 16 + kk;
            a = fmaf(Gc[k], Ws[k * 32 + o], a);
        }
        red[p * 32 + o] = a;
    }
    __syncthreads();
    if (t < 32) {
        float a = 0.f;
#pragma unroll
        for (int p = 0; p < 8; ++p) a += red[p * 32 + t];
        orow[t] = a;
    }
    __syncthreads();

    // broadcast to this block's 32 rows; fully-linear float4 stores (4 KB)
    {
        const int row = slice * 32 + (t >> 3);
        ((float4*)out)[((size_t)b * NN + row) * 8 + (t & 7)] =
            ((const float4*)orow)[t & 7];
    }
}

extern "C" void kernel_launch(void* const* d_in, const int* in_sizes, int n_in,
                              void* d_out, int out_size, void* d_ws, size_t ws_size,
                              hipStream_t stream) {
    const float* x  = (const float*)d_in[0];
    const float* W1 = (const float*)d_in[1];
    const float* b1 = (const float*)d_in[2];
    const float* W2 = (const float*)d_in[3];
    const float* b2 = (const float*)d_in[4];
    const float* W3 = (const float*)d_in[5];
    const float* b3 = (const float*)d_in[6];
    const float* Wa = (const float*)d_in[7];
    // d_in[8] = ba: cancels in softmax, unused
    const float* Ws = (const float*)d_in[9];
    const float* bs = (const float*)d_in[10];
    float* out = (float*)d_out;

    unsigned int* ctr = (unsigned int*)d_ws;             // 4 B, memset to 0
    float* Gp = (float*)d_ws + 64;                       // [256][128]
    float* Zp = Gp + NB * 128;                           // [256][4]

    hipMemsetAsync(ctr, 0, sizeof(unsigned int), stream);
    gat_fused<<<dim3(NB), dim3(256), 0, stream>>>(
        x, W1, b1, W2, b2, W3, b3, Wa, Ws, bs, Gp, Zp, ctr, out);
}

// Round 5
// 82.014 us; speedup vs baseline: 1.1994x; 1.1994x over previous
//
#include <hip/hip_runtime.h>

// GAT layer, B=8, N=1024, INP=7, hidden=64, D=32, H=4.
// Algebra: softmax_j(s_i + s_j + ba) == softmax_j(s_j) (shift-invariance), so
// attention weights and G[b,h,:] = sum_j p[j,h] fx[j,:] are i-independent;
// every output row of batch b equals (concat_h G[b,h,:]/Z[b,h]) @ Ws + bs.
//
// R5: two-kernel structure (R3) restored -- R4's fused grid barrier cost
// +14.7 us: per-block agent-scope fences emit buffer_wbl2/buffer_inv on
// non-coherent per-XCD L2s (256-block cache-op storm). A kernel boundary is
// ONE batched device-scope release -- cheaper. k1 layer2/3 remapped to fewer
// threads x more accumulators to cut ds_read_b128 count ~40% (LDS-pipe bound).

#define BB 8
#define NN 1024
#define TR 32            // rows per k1 block
#define NB1 256          // k1 blocks = 8192/TR; 32 blocks per batch

// ---------------------------------------------------------------------------
// k1: 256 blocks x 256 threads. MLP for a 32-row tile + e=exp(s_j) + partial
// G (4x32) and Z (4) written to ws[blk].
// ---------------------------------------------------------------------------
__global__ __launch_bounds__(256) void gat_k1(
    const float* __restrict__ x,
    const float* __restrict__ W1, const float* __restrict__ b1,
    const float* __restrict__ W2, const float* __restrict__ b2,
    const float* __restrict__ W3, const float* __restrict__ b3,
    const float* __restrict__ Wa,
    float* __restrict__ Gp, float* __restrict__ Zp)
{
    const int t   = threadIdx.x;
    const int blk = blockIdx.x;

    __shared__ float W1s[7 * 64];     // [k][o]
    __shared__ float W2s[64 * 64];    // [k][o]
    __shared__ float W3s[64 * 32];    // [k][o]
    __shared__ float Was[32 * 4];     // Wa rows 32..63: [k][h]
    __shared__ float b1s[64], b2s[64], b3s[32];
    __shared__ float xs[TR * 8];      // [r][k], stride 8
    __shared__ float h1s[TR * 68];    // stride 68 (pad 4, keeps 16B align)
    __shared__ float h2s[TR * 68];
    __shared__ float fxs[TR * 36];    // stride 36
    __shared__ float es[TR * 4];      // e[r][h]

    // ---- stage weights + x tile ----
    {
        const float4* s2 = (const float4*)W2;
        float4* d2 = (float4*)W2s;
        d2[t] = s2[t]; d2[t + 256] = s2[t + 256];
        d2[t + 512] = s2[t + 512]; d2[t + 768] = s2[t + 768];
        const float4* s3 = (const float4*)W3;
        float4* d3 = (float4*)W3s;
        d3[t] = s3[t]; d3[t + 256] = s3[t + 256];
        if (t < 112) ((float4*)W1s)[t] = ((const float4*)W1)[t];
        if (t < 32)  ((float4*)Was)[t] = ((const float4*)Wa)[32 + t]; // rows 32..63
        if (t < 16)  ((float4*)b1s)[t] = ((const float4*)b1)[t];
        if (t >= 16 && t < 32) ((float4*)b2s)[t - 16] = ((const float4*)b2)[t - 16];
        if (t >= 32 && t < 40) ((float4*)b3s)[t - 32] = ((const float4*)b3)[t - 32];
        if (t < TR * 7) xs[(t / 7) * 8 + (t % 7)] = x[blk * (TR * 7) + t];
    }
    __syncthreads();

    // ---- layer 1: [7]->[64], lrelu. 256 thr: 1 row x 8 cols ----
    {
        const int r  = t >> 3;
        const int o0 = (t & 7) * 8;
        float acc[8];
#pragma unroll
        for (int j = 0; j < 8; ++j) acc[j] = b1s[o0 + j];
#pragma unroll
        for (int k = 0; k < 7; ++k) {
            const float xv = xs[r * 8 + k];
#pragma unroll
            for (int j = 0; j < 8; ++j)
                acc[j] = fmaf(xv, W1s[k * 64 + o0 + j], acc[j]);
        }
#pragma unroll
        for (int j = 0; j < 8; ++j)
            h1s[r * 68 + o0 + j] = fmaxf(acc[j], 0.2f * acc[j]);
    }
    __syncthreads();

    // ---- layer 2: [64]->[64], lrelu. 128 thr: 4 rows x 4 cols ----
    // 8 ds_read_b128 per 64 FMA (vs 6 per 32 in R3) -> ~3072 ds-cyc/block.
    if (t < 128) {
        const int o0 = (t & 15) * 4;
        const int r0 = (t >> 4) * 4;
        float a[4][4];
#pragma unroll
        for (int i = 0; i < 4; ++i)
#pragma unroll
            for (int j = 0; j < 4; ++j) a[i][j] = b2s[o0 + j];
#pragma unroll
        for (int k4 = 0; k4 < 64; k4 += 4) {
            float hv[4][4];
#pragma unroll
            for (int i = 0; i < 4; ++i) {
                const float4 h4 = *(const float4*)&h1s[(r0 + i) * 68 + k4];
                hv[i][0] = h4.x; hv[i][1] = h4.y; hv[i][2] = h4.z; hv[i][3] = h4.w;
            }
#pragma unroll
            for (int kk = 0; kk < 4; ++kk) {
                const float4 w = *(const float4*)&W2s[(k4 + kk) * 64 + o0];
#pragma unroll
                for (int i = 0; i < 4; ++i) {
                    a[i][0] = fmaf(hv[i][kk], w.x, a[i][0]);
                    a[i][1] = fmaf(hv[i][kk], w.y, a[i][1]);
                    a[i][2] = fmaf(hv[i][kk], w.z, a[i][2]);
                    a[i][3] = fmaf(hv[i][kk], w.w, a[i][3]);
                }
            }
        }
#pragma unroll
        for (int i = 0; i < 4; ++i)
            *(float4*)&h2s[(r0 + i) * 68 + o0] = make_float4(
                fmaxf(a[i][0], 0.2f * a[i][0]), fmaxf(a[i][1], 0.2f * a[i][1]),
                fmaxf(a[i][2], 0.2f * a[i][2]), fmaxf(a[i][3], 0.2f * a[i][3]));
    }
    __syncthreads();

    // ---- layer 3: [64]->[32]. 128 thr: 2 rows x 4 cols ----
    if (t < 128) {
        const int o0 = (t & 7) * 4;
        const int r0 = (t >> 3) * 2;
        float a[2][4];
#pragma unroll
        for (int i = 0; i < 2; ++i)
#pragma unroll
            for (int j = 0; j < 4; ++j) a[i][j] = b3s[o0 + j];
#pragma unroll
        for (int k4 = 0; k4 < 64; k4 += 4) {
            float hv[2][4];
#pragma unroll
            for (int i = 0; i < 2; ++i) {
                const float4 h4 = *(const float4*)&h2s[(r0 + i) * 68 + k4];
                hv[i][0] = h4.x; hv[i][1] = h4.y; hv[i][2] = h4.z; hv[i][3] = h4.w;
            }
#pragma unroll
            for (int kk = 0; kk < 4; ++kk) {
                const float4 w = *(const float4*)&W3s[(k4 + kk) * 32 + o0];
#pragma unroll
                for (int i = 0; i < 2; ++i) {
                    a[i][0] = fmaf(hv[i][kk], w.x, a[i][0]);
                    a[i][1] = fmaf(hv[i][kk], w.y, a[i][1]);
                    a[i][2] = fmaf(hv[i][kk], w.z, a[i][2]);
                    a[i][3] = fmaf(hv[i][kk], w.w, a[i][3]);
                }
            }
        }
#pragma unroll
        for (int i = 0; i < 2; ++i)
            *(float4*)&fxs[(r0 + i) * 36 + o0] =
                make_float4(a[i][0], a[i][1], a[i][2], a[i][3]);
    }
    __syncthreads();

    // ---- e[r][h] = exp(fx[r,:] . Wa2[:,h])  (no max-sub: s_j is O(1)) ----
    if (t < TR * 4) {
        const int r = t >> 2, h = t & 3;
        float s = 0.f;
#pragma unroll 8
        for (int k = 0; k < 32; ++k) s = fmaf(fxs[r * 36 + k], Was[k * 4 + h], s);
        es[r * 4 + h] = __expf(s);
    }
    __syncthreads();

    // ---- block partials: G[h][d] (128 threads), Z[h] (4 threads) ----
    if (t < 128) {
        const int h = t >> 5, d = t & 31;
        float g = 0.f;
#pragma unroll 8
        for (int r = 0; r < TR; ++r) g = fmaf(es[r * 4 + h], fxs[r * 36 + d], g);
        Gp[blk * 128 + t] = g;
    } else if (t < 132) {
        const int h = t - 128;
        float z = 0.f;
#pragma unroll 8
        for (int r = 0; r < TR; ++r) z += es[r * 4 + h];
        Zp[blk * 4 + h] = z;
    }
}

// ---------------------------------------------------------------------------
// k2: 128 blocks x 256 threads (16 slices/batch). Reduce 32 partials,
// normalize, project through Ws, broadcast 64 rows.
// ---------------------------------------------------------------------------
__global__ __launch_bounds__(256) void gat_k2(
    const float* __restrict__ Gp, const float* __restrict__ Zp,
    const float* __restrict__ Ws, const float* __restrict__ bs,
    float* __restrict__ out)
{
    const int blk   = blockIdx.x;
    const int b     = blk >> 4;
    const int slice = blk & 15;
    const int t     = threadIdx.x;

    __shared__ float Gc[128];
    __shared__ float zsh[4];
    __shared__ float red[8 * 32];
    __shared__ float orow[32];

    float g = 0.f;
    if (t < 128) {
        const float* gp = Gp + (size_t)(b * 32) * 128 + t;
#pragma unroll 8
        for (int i = 0; i < 32; ++i) g += gp[i * 128];
    } else if (t < 132) {
        const int h = t - 128;
        float z = 0.f;
#pragma unroll 8
        for (int i = 0; i < 32; ++i) z += Zp[(b * 32 + i) * 4 + h];
        zsh[h] = z;
    }
    __syncthreads();
    if (t < 128) Gc[t] = g / zsh[t >> 5];
    __syncthreads();

    // orow[o] = bs[o] + sum_k Gc[k] * Ws[k*32+o]; k split over 8 groups
    {
        const int o = t & 31, p = t >> 5;
        float a = (p == 0) ? bs[o] : 0.f;
#pragma unroll
        for (int kk = 0; kk < 16; ++kk) {
            const int k = p * 16 + kk;
            a = fmaf(Gc[k], Ws[k * 32 + o], a);
        }
        red[p * 32 + o] = a;
    }
    __syncthreads();
    if (t < 32) {
        float a = 0.f;
#pragma unroll
        for (int p = 0; p < 8; ++p) a += red[p * 32 + t];
        orow[t] = a;
    }
    __syncthreads();

    // broadcast to 64 rows (2 per thread), fully-linear float4 stores
    const float4 v4 = ((const float4*)orow)[t & 7];
    const int rl = t >> 3;                 // 0..31
    const int row0 = slice * 64 + rl;
    ((float4*)out)[((size_t)b * NN + row0) * 8 + (t & 7)] = v4;
    ((float4*)out)[((size_t)b * NN + row0 + 32) * 8 + (t & 7)] = v4;
}

extern "C" void kernel_launch(void* const* d_in, const int* in_sizes, int n_in,
                              void* d_out, int out_size, void* d_ws, size_t ws_size,
                              hipStream_t stream) {
    const float* x  = (const float*)d_in[0];
    const float* W1 = (const float*)d_in[1];
    const float* b1 = (const float*)d_in[2];
    const float* W2 = (const float*)d_in[3];
    const float* b2 = (const float*)d_in[4];
    const float* W3 = (const float*)d_in[5];
    const float* b3 = (const float*)d_in[6];
    const float* Wa = (const float*)d_in[7];
    // d_in[8] = ba: cancels in softmax, unused
    const float* Ws = (const float*)d_in[9];
    const float* bs = (const float*)d_in[10];
    float* out = (float*)d_out;

    float* Gp = (float*)d_ws;                 // [256][128]
    float* Zp = Gp + NB1 * 128;               // [256][4]

    gat_k1<<<dim3(NB1), dim3(256), 0, stream>>>(
        x, W1, b1, W2, b2, W3, b3, Wa, Gp, Zp);
    gat_k2<<<dim3(128), dim3(256), 0, stream>>>(Gp, Zp, Ws, bs, out);
}